// Round 1
// baseline (512.504 us; speedup 1.0000x reference)
//
#include <hip/hip_runtime.h>
#include <cmath>

#define NN 8192
#define FIN 512
#define FD 64
#define LRALPHA 0.2f

#define ITILE 256
#define JC 32
#define JSPLIT 16
#define JRANGE (NN / JSPLIT)     // 512
#define NCHUNK (JRANGE / JC)     // 16

// ---------------- kernel 1: h = x@W ; src = h@a[:64] ; dst = h@a[64:] --------
// 256 threads = 4 waves, each wave owns 8 rows (lane = output feature f).
__global__ __launch_bounds__(256) void k_proj(const float* __restrict__ x,
        const float* __restrict__ W, const float* __restrict__ a,
        float* __restrict__ h, float* __restrict__ src, float* __restrict__ dst)
{
    const int t = threadIdx.x;
    const int lane = t & 63;
    const int wv = t >> 6;
    const int row0 = blockIdx.x * 32 + wv * 8;

    const float a1 = a[lane];
    const float a2 = a[FD + lane];

    float acc[8] = {0.f,0.f,0.f,0.f,0.f,0.f,0.f,0.f};
    for (int k0 = 0; k0 < FIN; k0 += 4) {
        const float w0 = W[(k0+0)*FD + lane];   // coalesced 256B across wave
        const float w1 = W[(k0+1)*FD + lane];
        const float w2 = W[(k0+2)*FD + lane];
        const float w3 = W[(k0+3)*FD + lane];
        #pragma unroll
        for (int r = 0; r < 8; ++r) {
            const float4 xv = *reinterpret_cast<const float4*>(&x[(size_t)(row0+r)*FIN + k0]);
            float s = acc[r];
            s = fmaf(xv.x, w0, s);
            s = fmaf(xv.y, w1, s);
            s = fmaf(xv.z, w2, s);
            s = fmaf(xv.w, w3, s);
            acc[r] = s;
        }
    }
    #pragma unroll
    for (int r = 0; r < 8; ++r) {
        h[(size_t)(row0+r)*FD + lane] = acc[r];
        float p1 = acc[r] * a1;
        float p2 = acc[r] * a2;
        #pragma unroll
        for (int s = 32; s > 0; s >>= 1) {
            p1 += __shfl_xor(p1, s, 64);
            p2 += __shfl_xor(p2, s, 64);
        }
        if (lane == 0) { src[row0+r] = p1; dst[row0+r] = p2; }
    }
}

// ---------------- kernel 2: fused mask+softmax-numerator+PV ------------------
// grid = (8192/ITILE) * JSPLIT = 32*16 = 512 blocks, 256 threads.
// Per chunk: gen weights from register-prefetched adj -> XOR-swizzled wlds,
// stage h chunk -> hlds, then 8x8 register-blocked f32 accumulation.
__global__ __launch_bounds__(256, 2) void k_attn(const int* __restrict__ adj,
        const float* __restrict__ h, const float* __restrict__ src,
        const float* __restrict__ dst, float* __restrict__ wsacc,
        float* __restrict__ wsden)
{
    __shared__ alignas(16) float wlds[ITILE][JC];   // XOR-swizzled in 16B granules
    __shared__ alignas(16) float hlds[JC][FD];
    __shared__ float srcl[ITILE];
    __shared__ float denl[ITILE];

    const int t = threadIdx.x;
    const int rb = blockIdx.x >> 4;          // row block 0..31
    const int jb = blockIdx.x & (JSPLIT-1);  // j split 0..15
    const int i0 = rb * ITILE;
    const int jbase = jb * JRANGE;

    srcl[t] = src[i0 + t];
    denl[t] = 0.f;

    const int fq = t & 7;        // compute-phase f-group  (f = fq*8 .. +7)
    const int rg = t >> 3;       // compute-phase row-group (rows rg*8 .. +7)
    const int gc4 = t & 7;       // gen-phase col quad (cols gc4*4 .. +3), const over k
    const int grow0 = t >> 3;    // gen-phase base row (+32 per k)

    float acc[8][8];
    #pragma unroll
    for (int r = 0; r < 8; ++r)
        #pragma unroll
        for (int f = 0; f < 8; ++f) acc[r][f] = 0.f;

    int4 adjr[8];
    float4 hr[2];
    float4 dstr;

    {   // prefetch chunk 0
        const int j0 = jbase;
        #pragma unroll
        for (int k = 0; k < 8; ++k)
            adjr[k] = *reinterpret_cast<const int4*>(&adj[(size_t)(i0 + grow0 + 32*k)*NN + j0 + gc4*4]);
        #pragma unroll
        for (int k = 0; k < 2; ++k) {
            const int p = t + k*256;
            hr[k] = *reinterpret_cast<const float4*>(&h[(size_t)(j0 + (p>>4))*FD + (p&15)*4]);
        }
        dstr = *reinterpret_cast<const float4*>(&dst[j0 + gc4*4]);
    }

    __syncthreads();   // srcl visible

    for (int c = 0; c < NCHUNK; ++c) {
        // ---- gen phase: registers -> weights in LDS + row denominators ----
        #pragma unroll
        for (int k = 0; k < 8; ++k) {
            const int row = grow0 + 32*k;
            const float sv = srcl[row];
            float4 wv; float e;
            e = sv + dstr.x; e = (e > 0.f) ? e : LRALPHA*e; wv.x = (adjr[k].x > 0) ? __expf(e) : 0.f;
            e = sv + dstr.y; e = (e > 0.f) ? e : LRALPHA*e; wv.y = (adjr[k].y > 0) ? __expf(e) : 0.f;
            e = sv + dstr.z; e = (e > 0.f) ? e : LRALPHA*e; wv.z = (adjr[k].z > 0) ? __expf(e) : 0.f;
            e = sv + dstr.w; e = (e > 0.f) ? e : LRALPHA*e; wv.w = (adjr[k].w > 0) ? __expf(e) : 0.f;
            float rsum = (wv.x + wv.y) + (wv.z + wv.w);
            rsum += __shfl_xor(rsum, 1, 64);   // reduce across the 8 col-quad lanes
            rsum += __shfl_xor(rsum, 2, 64);
            rsum += __shfl_xor(rsum, 4, 64);
            if (gc4 == 0) denl[row] += rsum;   // unique writer per row per chunk
            // 16B-granule XOR swizzle so compute-phase 8-row-stride reads are conflict-free
            *reinterpret_cast<float4*>(&wlds[row][(gc4 ^ ((row >> 3) & 7)) * 4]) = wv;
        }
        #pragma unroll
        for (int k = 0; k < 2; ++k) {
            const int p = t + k*256;
            *reinterpret_cast<float4*>(&hlds[p>>4][(p&15)*4]) = hr[k];
        }
        // ---- async-stage prefetch of chunk c+1 (latency hides under compute) ----
        if (c + 1 < NCHUNK) {
            const int j0 = jbase + (c+1)*JC;
            #pragma unroll
            for (int k = 0; k < 8; ++k)
                adjr[k] = *reinterpret_cast<const int4*>(&adj[(size_t)(i0 + grow0 + 32*k)*NN + j0 + gc4*4]);
            #pragma unroll
            for (int k = 0; k < 2; ++k) {
                const int p = t + k*256;
                hr[k] = *reinterpret_cast<const float4*>(&h[(size_t)(j0 + (p>>4))*FD + (p&15)*4]);
            }
            dstr = *reinterpret_cast<const float4*>(&dst[j0 + gc4*4]);
        }
        __syncthreads();   // wlds/hlds ready
        // ---- compute phase: acc[8r][8f] += w[row][l] * h[l][f] ----
        #pragma unroll
        for (int l0 = 0; l0 < JC; l0 += 4) {
            float4 ha[4], hb[4];
            #pragma unroll
            for (int l = 0; l < 4; ++l) {
                ha[l] = *reinterpret_cast<const float4*>(&hlds[l0+l][fq*8]);
                hb[l] = *reinterpret_cast<const float4*>(&hlds[l0+l][fq*8+4]);
            }
            const int swz = ((l0 >> 2) ^ (rg & 7)) * 4;
            #pragma unroll
            for (int r = 0; r < 8; ++r) {
                const float4 w4 = *reinterpret_cast<const float4*>(&wlds[rg*8 + r][swz]);
                const float wlv[4] = {w4.x, w4.y, w4.z, w4.w};
                #pragma unroll
                for (int l = 0; l < 4; ++l) {
                    acc[r][0] = fmaf(wlv[l], ha[l].x, acc[r][0]);
                    acc[r][1] = fmaf(wlv[l], ha[l].y, acc[r][1]);
                    acc[r][2] = fmaf(wlv[l], ha[l].z, acc[r][2]);
                    acc[r][3] = fmaf(wlv[l], ha[l].w, acc[r][3]);
                    acc[r][4] = fmaf(wlv[l], hb[l].x, acc[r][4]);
                    acc[r][5] = fmaf(wlv[l], hb[l].y, acc[r][5]);
                    acc[r][6] = fmaf(wlv[l], hb[l].z, acc[r][6]);
                    acc[r][7] = fmaf(wlv[l], hb[l].w, acc[r][7]);
                }
            }
        }
        __syncthreads();   // compute done before next gen overwrites LDS
    }

    // ---- flush partials (combined across j-split blocks) ----
    atomicAdd(&wsden[i0 + t], denl[t]);
    #pragma unroll
    for (int r = 0; r < 8; ++r) {
        const int row = i0 + rg*8 + r;
        #pragma unroll
        for (int f = 0; f < 8; ++f)
            atomicAdd(&wsacc[(size_t)row*FD + fq*8 + f], acc[r][f]);
    }
}

// ---------------- kernel 3: out = elu(acc/denom) -----------------------------
__global__ __launch_bounds__(256) void k_final(const float* __restrict__ wsacc,
        const float* __restrict__ wsden, float* __restrict__ out)
{
    const int idx = blockIdx.x * 256 + threadIdx.x;
    const int row = idx >> 6;
    const float v = wsacc[idx] / wsden[row];
    out[idx] = (v > 0.f) ? v : expm1f(v);
}

extern "C" void kernel_launch(void* const* d_in, const int* in_sizes, int n_in,
                              void* d_out, int out_size, void* d_ws, size_t ws_size,
                              hipStream_t stream) {
    const float* x   = (const float*)d_in[0];
    const int*   adj = (const int*)d_in[1];
    const float* W   = (const float*)d_in[2];
    const float* a   = (const float*)d_in[3];
    float* out = (float*)d_out;

    float* ws    = (float*)d_ws;
    float* wsacc = ws;                          // N*64 f32
    float* wsden = wsacc + (size_t)NN*FD;       // N f32
    float* h     = wsden + NN;                  // N*64 f32
    float* src   = h + (size_t)NN*FD;           // N f32
    float* dst   = src + NN;                    // N f32

    hipMemsetAsync(wsacc, 0, (size_t)(NN*FD + NN)*sizeof(float), stream);
    k_proj <<<256, 256, 0, stream>>>(x, W, a, h, src, dst);
    k_attn <<<32*JSPLIT, 256, 0, stream>>>(adj, h, src, dst, wsacc, wsden);
    k_final<<<NN*FD/256, 256, 0, stream>>>(wsacc, wsden, out);
}

// Round 2
// 131.002 us; speedup vs baseline: 3.9122x; 3.9122x over previous
//
#include <hip/hip_runtime.h>
#include <hip/hip_bf16.h>
#include <cmath>

#define NN 8192
#define FIN 512
#define FD 64
#define IT 16            // rows per k_attn block
#define JC 128           // j-chunk
#define NCH (NN / JC)    // 64 chunks

typedef __attribute__((ext_vector_type(4))) float f32x4;
typedef __attribute__((ext_vector_type(8))) short s16x8;

static __device__ __forceinline__ s16x8 as_s16x8(int4 v) {
    s16x8 r; __builtin_memcpy(&r, &v, 16); return r;
}
static __device__ __forceinline__ short bf16bits(float f) {
    __hip_bfloat16 h = __float2bfloat16(f);
    short s; __builtin_memcpy(&s, &h, 2); return s;
}

// ---------------- kernel 1: h = x@W (bf16, transposed) ; src/dst -------------
__global__ __launch_bounds__(256) void k_proj(const float* __restrict__ x,
        const float* __restrict__ W, const float* __restrict__ a,
        short* __restrict__ hT, float* __restrict__ src, float* __restrict__ dst)
{
    __shared__ short tl[32][64];
    const int t = threadIdx.x, lane = t & 63, wv = t >> 6;
    const int row0 = blockIdx.x * 32;
    const int r0 = wv * 8;
    const float a1 = a[lane], a2 = a[FD + lane];

    float acc[8] = {0.f,0.f,0.f,0.f,0.f,0.f,0.f,0.f};
    for (int k0 = 0; k0 < FIN; k0 += 4) {
        const float w0 = W[(k0+0)*FD + lane];
        const float w1 = W[(k0+1)*FD + lane];
        const float w2 = W[(k0+2)*FD + lane];
        const float w3 = W[(k0+3)*FD + lane];
        #pragma unroll
        for (int r = 0; r < 8; ++r) {
            const float4 xv = *reinterpret_cast<const float4*>(&x[(size_t)(row0+r0+r)*FIN + k0]);
            acc[r] = fmaf(xv.x, w0, fmaf(xv.y, w1, fmaf(xv.z, w2, fmaf(xv.w, w3, acc[r]))));
        }
    }
    #pragma unroll
    for (int r = 0; r < 8; ++r) {
        tl[r0 + r][lane] = bf16bits(acc[r]);
        float p1 = acc[r] * a1, p2 = acc[r] * a2;
        #pragma unroll
        for (int s = 32; s > 0; s >>= 1) { p1 += __shfl_xor(p1, s); p2 += __shfl_xor(p2, s); }
        if (lane == 0) { src[row0 + r0 + r] = p1; dst[row0 + r0 + r] = p2; }
    }
    __syncthreads();
    // transpose out: thread t -> feature f = t>>2, rows (t&3)*8 .. +8
    const int f = t >> 2, rr = (t & 3) * 8;
    alignas(16) short tmp[8];
    #pragma unroll
    for (int k = 0; k < 8; ++k) tmp[k] = tl[rr + k][f];
    *reinterpret_cast<int4*>(&hT[(size_t)f * NN + row0 + rr]) = *reinterpret_cast<int4*>(tmp);
}

// ---------------- kernel 2: fused gen + MFMA PV + softmax + ELU --------------
// 512 blocks x 256 thr. Block = 16 rows, full j sweep. Wave wv owns f-slice
// 16*wv..+16. Weight tile (16x128 bf16) generated once per chunk into
// XOR-swizzled LDS (unit u ^= row&7 on 16B units, both sides). B-frags read
// straight from L2-resident hT. 1-chunk-ahead named-register prefetch.
__global__ __launch_bounds__(256, 2) void k_attn(const int* __restrict__ adj,
        const short* __restrict__ hT, const float* __restrict__ src,
        const float* __restrict__ dst, float* __restrict__ out)
{
    __shared__ short wbuf[2][IT][JC];
    __shared__ float denl[IT];

    const int t = threadIdx.x;
    const int i0 = blockIdx.x * IT;
    const int row = t >> 4;          // gen-phase row 0..15
    const int q   = t & 15;          // gen-phase col group (8 cols)
    const int wv  = t >> 6;          // wave -> f-slice
    const int l   = t & 63;
    const int rA  = l & 15;          // mfma A row / B col(f)
    const int kg  = l >> 4;          // mfma k-group
    const int rx  = rA & 7;
    const int rbase = rA * JC;

    const float sv = src[i0 + row];
    float dsum = 0.f;
    f32x4 acc = {0.f, 0.f, 0.f, 0.f};

    const int4*   ap = (const int4*)(adj + (size_t)(i0 + row) * NN + q * 8);
    const float4* dp = (const float4*)(dst + q * 8);
    const int4*   hp = (const int4*)(hT + (size_t)(16 * wv + rA) * NN + kg * 8);

    short* wp0 = &wbuf[0][row][(q ^ (row & 7)) * 8];
    short* wp1 = &wbuf[1][row][(q ^ (row & 7)) * 8];
    const short* rb0 = &wbuf[0][0][0];
    const short* rb1 = &wbuf[1][0][0];

#define GEN(A0,A1,D0,D1,WP) do { \
    const int   ai[8] = {(A0).x,(A0).y,(A0).z,(A0).w,(A1).x,(A1).y,(A1).z,(A1).w}; \
    const float di[8] = {(D0).x,(D0).y,(D0).z,(D0).w,(D1).x,(D1).y,(D1).z,(D1).w}; \
    s16x8 pk; \
    _Pragma("unroll") \
    for (int e = 0; e < 8; ++e) { \
        float ev = sv + di[e]; \
        ev = fmaxf(ev, 0.2f * ev); \
        float wv_ = (ai[e] > 0) ? __expf(ev) : 0.f; \
        dsum += wv_; \
        pk[e] = bf16bits(wv_); \
    } \
    *reinterpret_cast<s16x8*>(WP) = pk; \
} while (0)

#define LOADSET(S, guard) do { if (guard) { \
    a##S##0 = ap[0]; a##S##1 = ap[1]; \
    d##S##0 = dp[0]; d##S##1 = dp[1]; \
    h##S##0 = hp[0]; h##S##1 = hp[4]; h##S##2 = hp[8]; h##S##3 = hp[12]; \
    ap += 32; dp += 32; hp += 16; } \
} while (0)

#define MM(RB, H0,H1,H2,H3) do { \
    s16x8 av; \
    av = *reinterpret_cast<const s16x8*>((RB) + rbase + ((((0*4)+kg) ^ rx) << 3)); \
    acc = __builtin_amdgcn_mfma_f32_16x16x32_bf16(av, as_s16x8(H0), acc, 0, 0, 0); \
    av = *reinterpret_cast<const s16x8*>((RB) + rbase + ((((1*4)+kg) ^ rx) << 3)); \
    acc = __builtin_amdgcn_mfma_f32_16x16x32_bf16(av, as_s16x8(H1), acc, 0, 0, 0); \
    av = *reinterpret_cast<const s16x8*>((RB) + rbase + ((((2*4)+kg) ^ rx) << 3)); \
    acc = __builtin_amdgcn_mfma_f32_16x16x32_bf16(av, as_s16x8(H2), acc, 0, 0, 0); \
    av = *reinterpret_cast<const s16x8*>((RB) + rbase + ((((3*4)+kg) ^ rx) << 3)); \
    acc = __builtin_amdgcn_mfma_f32_16x16x32_bf16(av, as_s16x8(H3), acc, 0, 0, 0); \
} while (0)

    // prefetch chunk 0 into set A
    int4 aA0 = ap[0], aA1 = ap[1];
    float4 dA0 = dp[0], dA1 = dp[1];
    int4 hA0 = hp[0], hA1 = hp[4], hA2 = hp[8], hA3 = hp[12];
    ap += 32; dp += 32; hp += 16;
    int4 aB0, aB1; float4 dB0, dB1; int4 hB0, hB1, hB2, hB3;

    for (int c = 0; c < NCH; c += 2) {
        GEN(aA0, aA1, dA0, dA1, wp0);
        LOADSET(B, (c + 1) < NCH);
        __syncthreads();
        MM(rb0, hA0, hA1, hA2, hA3);
        __syncthreads();
        GEN(aB0, aB1, dB0, dB1, wp1);
        LOADSET(A, (c + 2) < NCH);
        __syncthreads();
        MM(rb1, hB0, hB1, hB2, hB3);
        __syncthreads();
    }

#undef GEN
#undef LOADSET
#undef MM

    // denominator: reduce the 16 q-lanes of each row
    float d2 = dsum;
    d2 += __shfl_xor(d2, 1);
    d2 += __shfl_xor(d2, 2);
    d2 += __shfl_xor(d2, 4);
    d2 += __shfl_xor(d2, 8);
    if (q == 0) denl[row] = d2;
    __syncthreads();

    // epilogue: C layout col=lane&15, row=(lane>>4)*4+reg  -> divide, ELU, store
    const int fcol = 16 * wv + rA;
    #pragma unroll
    for (int j = 0; j < 4; ++j) {
        const int r = kg * 4 + j;
        float v = acc[j] / denl[r];
        v = (v > 0.f) ? v : expm1f(v);
        out[(size_t)(i0 + r) * FD + fcol] = v;
    }
}

extern "C" void kernel_launch(void* const* d_in, const int* in_sizes, int n_in,
                              void* d_out, int out_size, void* d_ws, size_t ws_size,
                              hipStream_t stream) {
    const float* x   = (const float*)d_in[0];
    const int*   adj = (const int*)d_in[1];
    const float* W   = (const float*)d_in[2];
    const float* a   = (const float*)d_in[3];
    float* out = (float*)d_out;

    short* hT  = (short*)d_ws;                                   // 64 x 8192 bf16 = 1 MB
    float* src = (float*)((char*)d_ws + (size_t)FD * NN * 2);    // 8192 f32
    float* dst = src + NN;                                       // 8192 f32

    k_proj<<<NN / 32, 256, 0, stream>>>(x, W, a, hT, src, dst);
    k_attn<<<NN / IT, 256, 0, stream>>>(adj, hT, src, dst, out);
}